// Round 12
// baseline (312.723 us; speedup 1.0000x reference)
//
#include <hip/hip_runtime.h>
#include <math.h>

#define S_PAST 8192
#define S_TOT  8193
#define HID    4096
#define NH     32
#define HD     128
#define INNER  16384
#define CH     16
#define NCH    512                       // 512*16 = 8192; last block takes 17 rows
#define ALPHA_ 7.483314773547883f        // sqrt(2*28)
#define INV_COEFF 0.08838834764831845f   // 1/(sqrt(128)*1)
#define EPS_ 1e-5f

typedef float vf4 __attribute__((ext_vector_type(4)));

// ---------------- LayerNorm: 1 block, 256 threads, H=4096 ----------------
__global__ __launch_bounds__(256) void ln_kernel(const float* __restrict__ xin,
                                                 const float* __restrict__ w,
                                                 const float* __restrict__ b,
                                                 float* __restrict__ out) {
    int tid = threadIdx.x;
    float xs[16];
    float s = 0.f, s2 = 0.f;
#pragma unroll
    for (int i = 0; i < 16; ++i) {
        float v = xin[tid + i * 256];
        xs[i] = v; s += v; s2 += v * v;
    }
    for (int off = 32; off; off >>= 1) {
        s  += __shfl_down(s, off, 64);
        s2 += __shfl_down(s2, off, 64);
    }
    __shared__ float rs[4], rs2[4];
    __shared__ float mu_s, ri_s;
    int wid = tid >> 6, lane = tid & 63;
    if (lane == 0) { rs[wid] = s; rs2[wid] = s2; }
    __syncthreads();
    if (tid == 0) {
        float S1 = rs[0] + rs[1] + rs[2] + rs[3];
        float S2 = rs2[0] + rs2[1] + rs2[2] + rs2[3];
        float mu = S1 / HID;
        float var = S2 / HID - mu * mu;
        mu_s = mu;
        ri_s = rsqrtf(var + EPS_);
    }
    __syncthreads();
    float mu = mu_s, ri = ri_s;
#pragma unroll
    for (int i = 0; i < 16; ++i) {
        int idx = tid + i * 256;
        out[idx] = (xs[i] - mu) * ri * w[idx] + b[idx];
    }
}

// ---------------- GEMV: one row per WAVE, 4 rows/block ----------------
// MODE 0: plain; 1: += ALPHA*res[r]; 2: gelu(tanh)
template <int C, int MODE>
__global__ __launch_bounds__(256) void gemv_kernel(
        const float* __restrict__ Wm, const float* __restrict__ bias,
        const float* __restrict__ x, float* __restrict__ y,
        const float* __restrict__ res) {
    int wid = threadIdx.x >> 6, lane = threadIdx.x & 63;
    int r = blockIdx.x * 4 + wid;
    const float4* __restrict__ rowv = (const float4*)(Wm + (size_t)r * C);
    const float4* __restrict__ xv = (const float4*)x;
    constexpr int IT = C / 4 / 64;   // 16 (C=4096) or 64 (C=16384)
    float acc0 = 0.f, acc1 = 0.f;
#pragma unroll 8
    for (int it = 0; it < IT; it += 2) {
        float4 w0 = rowv[lane + it * 64];
        float4 x0 = xv[lane + it * 64];
        float4 w1 = rowv[lane + (it + 1) * 64];
        float4 x1 = xv[lane + (it + 1) * 64];
        acc0 += w0.x * x0.x + w0.y * x0.y + w0.z * x0.z + w0.w * x0.w;
        acc1 += w1.x * x1.x + w1.y * x1.y + w1.z * x1.z + w1.w * x1.w;
    }
    float acc = acc0 + acc1;
    for (int off = 32; off; off >>= 1) acc += __shfl_down(acc, off, 64);
    if (lane == 0) {
        float t = acc + bias[r];
        if (MODE == 1) t += ALPHA_ * res[r];
        if (MODE == 2) {
            float u = t;
            t = 0.5f * u * (1.f + tanhf(0.7978845608028654f * (u + 0.044715f * u * u * u)));
        }
        y[r] = t;
    }
}

// ---------------- RoPE + append new k/v row (qrot pre-scaled) ----------------
__global__ __launch_bounds__(128) void rope_kv_kernel(
        const float* __restrict__ qkv, const float* __restrict__ cosc,
        const float* __restrict__ sinc, const int* __restrict__ pos_ids,
        const int* __restrict__ blk_ids, float* __restrict__ qrot,
        float* __restrict__ kout, float* __restrict__ vout) {
    int h = blockIdx.x, d = threadIdx.x;     // d in [0,128)
    int pos = pos_ids[0], blk = blk_ids[0];
    const float* qh = qkv + h * 384;         // [q(128) | k(128) | v(128)]
    float q = qh[d], k = qh[128 + d], v = qh[256 + d];
    int half = d >> 6;                       // 0 -> pos rope, 1 -> blk rope
    int i = d & 63;
    int p = half ? blk : pos;
    float c = cosc[p * 64 + i];
    float s = sinc[p * 64 + i];
    float qpart, kpart;
    int base = half * 64;
    if (i < 32) { qpart = -qh[base + i + 32]; kpart = -qh[128 + base + i + 32]; }
    else        { qpart =  qh[base + i - 32]; kpart =  qh[128 + base + i - 32]; }
    float qo = q * c + qpart * s;
    float ko = k * c + kpart * s;
    qrot[h * HD + d] = qo * INV_COEFF;       // fold 1/(sqrt(128)*coeff)
    size_t o = (size_t)S_PAST * HID + h * HD + d;
    kout[o] = ko;
    vout[o] = v;
}

// ---- KV cache copy: clean read-stream + write-stream, nontemporal ----
// blocks [0, G/2) copy K, [G/2, G) copy V; grid-stride vf4.
#define COPY_GRID 2048
__global__ __launch_bounds__(256) void kv_copy(const vf4* __restrict__ pk,
                                               const vf4* __restrict__ pv,
                                               vf4* __restrict__ ko,
                                               vf4* __restrict__ vo) {
    const size_t n = (size_t)S_PAST * HID / 4;     // 8.39M vf4 per tensor
    int half = blockIdx.x >= (COPY_GRID / 2);
    const vf4* __restrict__ src = half ? pv : pk;
    vf4* __restrict__ dst = half ? vo : ko;
    size_t start = (size_t)(blockIdx.x - half * (COPY_GRID / 2)) * 256 + threadIdx.x;
    size_t stride = (size_t)(COPY_GRID / 2) * 256;
    for (size_t i = start; i < n; i += stride) {
        __builtin_nontemporal_store(__builtin_nontemporal_load(src + i), dst + i);
    }
}

// ---- single-pass READ-ONLY attention (copy split out): per row {K load, dot,
// butterfly, exp, V load, FMA}. No-max softmax (validated R7-R10). 512 threads:
// half u = rows [u*8, ...); thread t=tid&255 owns float4 columns {t,t+256,t+512,t+768};
// column 256g+t -> head 8g+(t>>5). Row 8192 read from kout/vout (written by rope).
__global__ __launch_bounds__(512) void attn_onepass(
        const float* __restrict__ qrot, const float* __restrict__ pastk,
        const float* __restrict__ pastv, const float* __restrict__ kout,
        const float* __restrict__ vout, const unsigned char* __restrict__ mask,
        float* __restrict__ pctx, float* __restrict__ pL) {
    int tid = threadIdx.x;
    int t = tid & 255, u = tid >> 8;
    int s0 = blockIdx.x * CH;
    int rows = (blockIdx.x == NCH - 1) ? (S_TOT - s0) : CH;   // 17 on last block
    int rstart = u * 8;
    int rend = u ? rows : 8;
    int a = t >> 5;
    const float4* __restrict__ qv = (const float4*)qrot;
    float4 q0 = qv[t], q1 = qv[256 + t], q2 = qv[512 + t], q3 = qv[768 + t];
    float4 a0 = {0,0,0,0}, a1 = {0,0,0,0}, a2 = {0,0,0,0}, a3 = {0,0,0,0};
    float eL0 = 0.f, eL1 = 0.f, eL2 = 0.f, eL3 = 0.f;
#pragma unroll 4
    for (int r = rstart; r < rend; ++r) {
        int srow = s0 + r;
        bool past = srow < S_PAST;
        const float* kbase = past ? pastk : kout;
        const float4* krow = (const float4*)(kbase + (size_t)srow * HID);
        float4 k0 = krow[t], k1 = krow[256 + t];
        float4 k2 = krow[512 + t], k3 = krow[768 + t];
        float d0 = q0.x * k0.x + q0.y * k0.y + q0.z * k0.z + q0.w * k0.w;
        float d1 = q1.x * k1.x + q1.y * k1.y + q1.z * k1.z + q1.w * k1.w;
        float d2 = q2.x * k2.x + q2.y * k2.y + q2.z * k2.z + q2.w * k2.w;
        float d3 = q3.x * k3.x + q3.y * k3.y + q3.z * k3.z + q3.w * k3.w;
#pragma unroll
        for (int off = 1; off < 32; off <<= 1) {
            d0 += __shfl_xor(d0, off, 64);
            d1 += __shfl_xor(d1, off, 64);
            d2 += __shfl_xor(d2, off, 64);
            d3 += __shfl_xor(d3, off, 64);
        }
        if (mask[srow]) { d0 = d1 = d2 = d3 = -10000.f; }
        float p0 = __expf(d0), p1 = __expf(d1), p2 = __expf(d2), p3 = __expf(d3);
        eL0 += p0; eL1 += p1; eL2 += p2; eL3 += p3;
        const float* vbase = past ? pastv : vout;
        const float4* vrow = (const float4*)(vbase + (size_t)srow * HID);
        float4 v0 = vrow[t], v1 = vrow[256 + t];
        float4 v2 = vrow[512 + t], v3 = vrow[768 + t];
        a0.x += p0 * v0.x; a0.y += p0 * v0.y; a0.z += p0 * v0.z; a0.w += p0 * v0.w;
        a1.x += p1 * v1.x; a1.y += p1 * v1.y; a1.z += p1 * v1.z; a1.w += p1 * v1.w;
        a2.x += p2 * v2.x; a2.y += p2 * v2.y; a2.z += p2 * v2.z; a2.w += p2 * v2.w;
        a3.x += p3 * v3.x; a3.y += p3 * v3.y; a3.z += p3 * v3.z; a3.w += p3 * v3.w;
    }
    __shared__ float acc_lds[256][16];
    __shared__ float eLds[2][8][4];
    if (u == 1) {
        acc_lds[t][0]  = a0.x; acc_lds[t][1]  = a0.y; acc_lds[t][2]  = a0.z; acc_lds[t][3]  = a0.w;
        acc_lds[t][4]  = a1.x; acc_lds[t][5]  = a1.y; acc_lds[t][6]  = a1.z; acc_lds[t][7]  = a1.w;
        acc_lds[t][8]  = a2.x; acc_lds[t][9]  = a2.y; acc_lds[t][10] = a2.z; acc_lds[t][11] = a2.w;
        acc_lds[t][12] = a3.x; acc_lds[t][13] = a3.y; acc_lds[t][14] = a3.z; acc_lds[t][15] = a3.w;
    }
    if ((t & 31) == 0) {
        eLds[u][a][0] = eL0; eLds[u][a][1] = eL1;
        eLds[u][a][2] = eL2; eLds[u][a][3] = eL3;
    }
    __syncthreads();
    if (u == 0) {
        a0.x += acc_lds[t][0];  a0.y += acc_lds[t][1];  a0.z += acc_lds[t][2];  a0.w += acc_lds[t][3];
        a1.x += acc_lds[t][4];  a1.y += acc_lds[t][5];  a1.z += acc_lds[t][6];  a1.w += acc_lds[t][7];
        a2.x += acc_lds[t][8];  a2.y += acc_lds[t][9];  a2.z += acc_lds[t][10]; a2.w += acc_lds[t][11];
        a3.x += acc_lds[t][12]; a3.y += acc_lds[t][13]; a3.z += acc_lds[t][14]; a3.w += acc_lds[t][15];
        float4* pc = (float4*)(pctx + (size_t)blockIdx.x * HID);
        pc[t] = a0; pc[256 + t] = a1; pc[512 + t] = a2; pc[768 + t] = a3;
    }
    if (tid < NH) {
        int ah = tid & 7, g = tid >> 3;
        pL[tid * NCH + blockIdx.x] = eLds[0][ah][g] + eLds[1][ah][g];
    }
}

// ---- single-stage reduce: 256 blocks; block b owns ctx[b*16 .. b*16+16) ----
// (16 idx never straddle a head: head boundary every 128.)
__global__ __launch_bounds__(256) void ctx_reduce(const float* __restrict__ pctx,
                                                  const float* __restrict__ pL,
                                                  float* __restrict__ ctx) {
    int b = blockIdx.x, t = threadIdx.x;
    int i0 = b * 16;
    int h = i0 >> 7;
    // per-head L: sum 512 chunk partials
    float e = pL[h * NCH + t] + pL[h * NCH + 256 + t];
    for (int off = 32; off; off >>= 1) e += __shfl_down(e, off, 64);
    __shared__ float ew[4];
    int wid = t >> 6, lane = t & 63;
    if (lane == 0) ew[wid] = e;
    // ctx partial: thread (r0, ii) sums rows r0+16k at column i0+ii
    int r0 = t >> 4, ii = t & 15;
    float a = 0.f;
    for (int r = r0; r < NCH; r += 16) a += pctx[(size_t)r * HID + i0 + ii];
    __shared__ float sc[16][17];
    sc[r0][ii] = a;
    __syncthreads();
    float Lh = ew[0] + ew[1] + ew[2] + ew[3];
    if (t < 16) {
        float s = 0.f;
#pragma unroll
        for (int r = 0; r < 16; ++r) s += sc[r][t];
        ctx[i0 + t] = s / Lh;
    }
}

extern "C" void kernel_launch(void* const* d_in, const int* in_sizes, int n_in,
                              void* d_out, int out_size, void* d_ws, size_t ws_size,
                              hipStream_t stream) {
    const float* hidden = (const float*)d_in[0];
    const float* past_k = (const float*)d_in[1];
    const float* past_v = (const float*)d_in[2];
    const float* cosc = (const float*)d_in[3];
    const float* sinc = (const float*)d_in[4];
    const float* ln1w = (const float*)d_in[5];
    const float* ln1b = (const float*)d_in[6];
    const float* qkvw = (const float*)d_in[7];
    const float* qkvb = (const float*)d_in[8];
    const float* denw = (const float*)d_in[9];
    const float* denb = (const float*)d_in[10];
    const float* ln2w = (const float*)d_in[11];
    const float* ln2b = (const float*)d_in[12];
    const float* fc1w = (const float*)d_in[13];
    const float* fc1b = (const float*)d_in[14];
    const float* fc2w = (const float*)d_in[15];
    const float* fc2b = (const float*)d_in[16];
    const int* pos = (const int*)d_in[17];
    const int* blk = (const int*)d_in[18];
    const unsigned char* mask = (const unsigned char*)d_in[19];

    float* out_f = (float*)d_out;
    float* kout = out_f + HID;                    // [8193,32,128]
    float* vout = kout + (size_t)S_TOT * HID;     // [8193,32,128]

    float* ws = (float*)d_ws;
    float* resid1 = ws;                     // 4096
    float* qkvv   = ws + 4096;              // 12288
    float* qrot   = ws + 16384;             // 4096
    float* ctx    = ws + 20480;             // 4096
    float* hid2   = ws + 24576;             // 4096
    float* resid2 = ws + 28672;             // 4096
    float* mlpi   = ws + 32768;             // 16384
    float* pL     = ws + 49152;             // 32*512 = 16384
    float* pctx   = ws + 65536;             // 512*4096 = 2097152  (~8.7 MB total)

    ln_kernel<<<1, 256, 0, stream>>>(hidden, ln1w, ln1b, resid1);
    gemv_kernel<HID, 0><<<3 * HID / 4, 256, 0, stream>>>(qkvw, qkvb, resid1, qkvv, nullptr);
    rope_kv_kernel<<<NH, HD, 0, stream>>>(qkvv, cosc, sinc, pos, blk, qrot, kout, vout);
    kv_copy<<<COPY_GRID, 256, 0, stream>>>((const vf4*)past_k, (const vf4*)past_v,
                                           (vf4*)kout, (vf4*)vout);
    attn_onepass<<<NCH, 512, 0, stream>>>(qrot, past_k, past_v, kout, vout, mask, pctx, pL);
    ctx_reduce<<<256, 256, 0, stream>>>(pctx, pL, ctx);
    gemv_kernel<HID, 1><<<HID / 4, 256, 0, stream>>>(denw, denb, ctx, hid2, resid1);
    ln_kernel<<<1, 256, 0, stream>>>(hid2, ln2w, ln2b, resid2);
    gemv_kernel<HID, 2><<<INNER / 4, 256, 0, stream>>>(fc1w, fc1b, resid2, mlpi, nullptr);
    gemv_kernel<INNER, 1><<<HID / 4, 256, 0, stream>>>(fc2w, fc2b, mlpi, out_f, resid2);
}

// Round 13
// 283.385 us; speedup vs baseline: 1.1035x; 1.1035x over previous
//
#include <hip/hip_runtime.h>
#include <math.h>

#define S_PAST 8192
#define S_TOT  8193
#define HID    4096
#define NH     32
#define HD     128
#define INNER  16384
#define CH     16
#define NCH    512                       // 512*16 = 8192; last block takes 17 rows
#define ALPHA_ 7.483314773547883f        // sqrt(2*28)
#define INV_COEFF 0.08838834764831845f   // 1/(sqrt(128)*1)
#define EPS_ 1e-5f

// ---------------- LayerNorm: 1 block, 256 threads, H=4096 ----------------
__global__ __launch_bounds__(256) void ln_kernel(const float* __restrict__ xin,
                                                 const float* __restrict__ w,
                                                 const float* __restrict__ b,
                                                 float* __restrict__ out) {
    int tid = threadIdx.x;
    float xs[16];
    float s = 0.f, s2 = 0.f;
#pragma unroll
    for (int i = 0; i < 16; ++i) {
        float v = xin[tid + i * 256];
        xs[i] = v; s += v; s2 += v * v;
    }
    for (int off = 32; off; off >>= 1) {
        s  += __shfl_down(s, off, 64);
        s2 += __shfl_down(s2, off, 64);
    }
    __shared__ float rs[4], rs2[4];
    __shared__ float mu_s, ri_s;
    int wid = tid >> 6, lane = tid & 63;
    if (lane == 0) { rs[wid] = s; rs2[wid] = s2; }
    __syncthreads();
    if (tid == 0) {
        float S1 = rs[0] + rs[1] + rs[2] + rs[3];
        float S2 = rs2[0] + rs2[1] + rs2[2] + rs2[3];
        float mu = S1 / HID;
        float var = S2 / HID - mu * mu;
        mu_s = mu;
        ri_s = rsqrtf(var + EPS_);
    }
    __syncthreads();
    float mu = mu_s, ri = ri_s;
#pragma unroll
    for (int i = 0; i < 16; ++i) {
        int idx = tid + i * 256;
        out[idx] = (xs[i] - mu) * ri * w[idx] + b[idx];
    }
}

// ---------------- GEMV: one row per WAVE, 4 rows/block ----------------
// MODE 0: plain; 1: += ALPHA*res[r]; 2: gelu(tanh)
template <int C, int MODE>
__global__ __launch_bounds__(256) void gemv_kernel(
        const float* __restrict__ Wm, const float* __restrict__ bias,
        const float* __restrict__ x, float* __restrict__ y,
        const float* __restrict__ res) {
    int wid = threadIdx.x >> 6, lane = threadIdx.x & 63;
    int r = blockIdx.x * 4 + wid;
    const float4* __restrict__ rowv = (const float4*)(Wm + (size_t)r * C);
    const float4* __restrict__ xv = (const float4*)x;
    constexpr int IT = C / 4 / 64;   // 16 for C=4096
    float acc0 = 0.f, acc1 = 0.f;
#pragma unroll 8
    for (int it = 0; it < IT; it += 2) {
        float4 w0 = rowv[lane + it * 64];
        float4 x0 = xv[lane + it * 64];
        float4 w1 = rowv[lane + (it + 1) * 64];
        float4 x1 = xv[lane + (it + 1) * 64];
        acc0 += w0.x * x0.x + w0.y * x0.y + w0.z * x0.z + w0.w * x0.w;
        acc1 += w1.x * x1.x + w1.y * x1.y + w1.z * x1.z + w1.w * x1.w;
    }
    float acc = acc0 + acc1;
    for (int off = 32; off; off >>= 1) acc += __shfl_down(acc, off, 64);
    if (lane == 0) {
        float t = acc + bias[r];
        if (MODE == 1) t += ALPHA_ * res[r];
        if (MODE == 2) {
            float u = t;
            t = 0.5f * u * (1.f + tanhf(0.7978845608028654f * (u + 0.044715f * u * u * u)));
        }
        y[r] = t;
    }
}

// ---- wide GEMV (C=16384): ONE row per block (4096 blocks -> smooth tail) ----
__global__ __launch_bounds__(256) void gemv_wide_kernel(
        const float* __restrict__ Wm, const float* __restrict__ bias,
        const float* __restrict__ x, float* __restrict__ y,
        const float* __restrict__ res) {
    int tid = threadIdx.x;
    int r = blockIdx.x;
    const float4* __restrict__ rowv = (const float4*)(Wm + (size_t)r * INNER);
    const float4* __restrict__ xv = (const float4*)x;
    float acc0 = 0.f, acc1 = 0.f;
#pragma unroll 8
    for (int it = 0; it < 16; it += 2) {
        float4 w0 = rowv[tid + it * 256];
        float4 x0 = xv[tid + it * 256];
        float4 w1 = rowv[tid + (it + 1) * 256];
        float4 x1 = xv[tid + (it + 1) * 256];
        acc0 += w0.x * x0.x + w0.y * x0.y + w0.z * x0.z + w0.w * x0.w;
        acc1 += w1.x * x1.x + w1.y * x1.y + w1.z * x1.z + w1.w * x1.w;
    }
    float acc = acc0 + acc1;
    for (int off = 32; off; off >>= 1) acc += __shfl_down(acc, off, 64);
    __shared__ float red[4];
    int wid = tid >> 6, lane = tid & 63;
    if (lane == 0) red[wid] = acc;
    __syncthreads();
    if (tid == 0) {
        float t = red[0] + red[1] + red[2] + red[3] + bias[r];
        t += ALPHA_ * res[r];
        y[r] = t;
    }
}

// ---------------- RoPE + append new k/v row (qrot pre-scaled) ----------------
__global__ __launch_bounds__(128) void rope_kv_kernel(
        const float* __restrict__ qkv, const float* __restrict__ cosc,
        const float* __restrict__ sinc, const int* __restrict__ pos_ids,
        const int* __restrict__ blk_ids, float* __restrict__ qrot,
        float* __restrict__ kout, float* __restrict__ vout) {
    int h = blockIdx.x, d = threadIdx.x;     // d in [0,128)
    int pos = pos_ids[0], blk = blk_ids[0];
    const float* qh = qkv + h * 384;         // [q(128) | k(128) | v(128)]
    float q = qh[d], k = qh[128 + d], v = qh[256 + d];
    int half = d >> 6;                       // 0 -> pos rope, 1 -> blk rope
    int i = d & 63;
    int p = half ? blk : pos;
    float c = cosc[p * 64 + i];
    float s = sinc[p * 64 + i];
    float qpart, kpart;
    int base = half * 64;
    if (i < 32) { qpart = -qh[base + i + 32]; kpart = -qh[128 + base + i + 32]; }
    else        { qpart =  qh[base + i - 32]; kpart =  qh[128 + base + i - 32]; }
    float qo = q * c + qpart * s;
    float ko = k * c + kpart * s;
    qrot[h * HD + d] = qo * INV_COEFF;       // fold 1/(sqrt(128)*coeff)
    size_t o = (size_t)S_PAST * HID + h * HD + d;
    kout[o] = ko;
    vout[o] = v;
}

// ---- fused single-pass attention + KV copy (R10 structure, best measured).
// V loads/writes hoisted NEXT TO K loads (no dep on the dot) so their latency
// hides under the 20-op shfl butterfly instead of serializing after it.
__global__ __launch_bounds__(512) void attn_onepass(
        const float* __restrict__ qrot, const float* __restrict__ pastk,
        const float* __restrict__ pastv, float* __restrict__ kout,
        float* __restrict__ vout, const unsigned char* __restrict__ mask,
        float* __restrict__ pctx, float* __restrict__ pL) {
    int tid = threadIdx.x;
    int t = tid & 255, u = tid >> 8;
    int s0 = blockIdx.x * CH;
    int rows = (blockIdx.x == NCH - 1) ? (S_TOT - s0) : CH;   // 17 on last block
    int rstart = u * 8;
    int rend = u ? rows : 8;
    int a = t >> 5;
    const float4* __restrict__ qv = (const float4*)qrot;
    float4 q0 = qv[t], q1 = qv[256 + t], q2 = qv[512 + t], q3 = qv[768 + t];
    float4 a0 = {0,0,0,0}, a1 = {0,0,0,0}, a2 = {0,0,0,0}, a3 = {0,0,0,0};
    float eL0 = 0.f, eL1 = 0.f, eL2 = 0.f, eL3 = 0.f;
#pragma unroll 4
    for (int r = rstart; r < rend; ++r) {
        int srow = s0 + r;
        bool past = srow < S_PAST;
        const float* kbase = past ? pastk : kout;
        const float* vbase = past ? pastv : vout;
        const float4* krow = (const float4*)(kbase + (size_t)srow * HID);
        const float4* vrow = (const float4*)(vbase + (size_t)srow * HID);
        // issue K and V loads together (V has no dependency on the dot)
        float4 k0 = krow[t], k1 = krow[256 + t];
        float4 k2 = krow[512 + t], k3 = krow[768 + t];
        float4 v0 = vrow[t], v1 = vrow[256 + t];
        float4 v2 = vrow[512 + t], v3 = vrow[768 + t];
        if (past) {
            float4* ko = (float4*)(kout + (size_t)srow * HID);
            ko[t] = k0; ko[256 + t] = k1; ko[512 + t] = k2; ko[768 + t] = k3;
            float4* vo = (float4*)(vout + (size_t)srow * HID);
            vo[t] = v0; vo[256 + t] = v1; vo[512 + t] = v2; vo[768 + t] = v3;
        }
        float d0 = q0.x * k0.x + q0.y * k0.y + q0.z * k0.z + q0.w * k0.w;
        float d1 = q1.x * k1.x + q1.y * k1.y + q1.z * k1.z + q1.w * k1.w;
        float d2 = q2.x * k2.x + q2.y * k2.y + q2.z * k2.z + q2.w * k2.w;
        float d3 = q3.x * k3.x + q3.y * k3.y + q3.z * k3.z + q3.w * k3.w;
#pragma unroll
        for (int off = 1; off < 32; off <<= 1) {
            d0 += __shfl_xor(d0, off, 64);
            d1 += __shfl_xor(d1, off, 64);
            d2 += __shfl_xor(d2, off, 64);
            d3 += __shfl_xor(d3, off, 64);
        }
        if (mask[srow]) { d0 = d1 = d2 = d3 = -10000.f; }
        float p0 = __expf(d0), p1 = __expf(d1), p2 = __expf(d2), p3 = __expf(d3);
        eL0 += p0; eL1 += p1; eL2 += p2; eL3 += p3;
        a0.x += p0 * v0.x; a0.y += p0 * v0.y; a0.z += p0 * v0.z; a0.w += p0 * v0.w;
        a1.x += p1 * v1.x; a1.y += p1 * v1.y; a1.z += p1 * v1.z; a1.w += p1 * v1.w;
        a2.x += p2 * v2.x; a2.y += p2 * v2.y; a2.z += p2 * v2.z; a2.w += p2 * v2.w;
        a3.x += p3 * v3.x; a3.y += p3 * v3.y; a3.z += p3 * v3.z; a3.w += p3 * v3.w;
    }
    __shared__ float acc_lds[256][16];
    __shared__ float eLds[2][8][4];
    if (u == 1) {
        acc_lds[t][0]  = a0.x; acc_lds[t][1]  = a0.y; acc_lds[t][2]  = a0.z; acc_lds[t][3]  = a0.w;
        acc_lds[t][4]  = a1.x; acc_lds[t][5]  = a1.y; acc_lds[t][6]  = a1.z; acc_lds[t][7]  = a1.w;
        acc_lds[t][8]  = a2.x; acc_lds[t][9]  = a2.y; acc_lds[t][10] = a2.z; acc_lds[t][11] = a2.w;
        acc_lds[t][12] = a3.x; acc_lds[t][13] = a3.y; acc_lds[t][14] = a3.z; acc_lds[t][15] = a3.w;
    }
    if ((t & 31) == 0) {
        eLds[u][a][0] = eL0; eLds[u][a][1] = eL1;
        eLds[u][a][2] = eL2; eLds[u][a][3] = eL3;
    }
    __syncthreads();
    if (u == 0) {
        a0.x += acc_lds[t][0];  a0.y += acc_lds[t][1];  a0.z += acc_lds[t][2];  a0.w += acc_lds[t][3];
        a1.x += acc_lds[t][4];  a1.y += acc_lds[t][5];  a1.z += acc_lds[t][6];  a1.w += acc_lds[t][7];
        a2.x += acc_lds[t][8];  a2.y += acc_lds[t][9];  a2.z += acc_lds[t][10]; a2.w += acc_lds[t][11];
        a3.x += acc_lds[t][12]; a3.y += acc_lds[t][13]; a3.z += acc_lds[t][14]; a3.w += acc_lds[t][15];
        float4* pc = (float4*)(pctx + (size_t)blockIdx.x * HID);
        pc[t] = a0; pc[256 + t] = a1; pc[512 + t] = a2; pc[768 + t] = a3;
    }
    if (tid < NH) {
        int ah = tid & 7, g = tid >> 3;
        pL[tid * NCH + blockIdx.x] = eLds[0][ah][g] + eLds[1][ah][g];
    }
}

// ---- single-stage reduce: 256 blocks; block b owns ctx[b*16 .. b*16+16) ----
__global__ __launch_bounds__(256) void ctx_reduce(const float* __restrict__ pctx,
                                                  const float* __restrict__ pL,
                                                  float* __restrict__ ctx) {
    int b = blockIdx.x, t = threadIdx.x;
    int i0 = b * 16;
    int h = i0 >> 7;
    float e = pL[h * NCH + t] + pL[h * NCH + 256 + t];
    for (int off = 32; off; off >>= 1) e += __shfl_down(e, off, 64);
    __shared__ float ew[4];
    int wid = t >> 6, lane = t & 63;
    if (lane == 0) ew[wid] = e;
    int r0 = t >> 4, ii = t & 15;
    float a = 0.f;
    for (int r = r0; r < NCH; r += 16) a += pctx[(size_t)r * HID + i0 + ii];
    __shared__ float sc[16][17];
    sc[r0][ii] = a;
    __syncthreads();
    float Lh = ew[0] + ew[1] + ew[2] + ew[3];
    if (t < 16) {
        float s = 0.f;
#pragma unroll
        for (int r = 0; r < 16; ++r) s += sc[r][t];
        ctx[i0 + t] = s / Lh;
    }
}

extern "C" void kernel_launch(void* const* d_in, const int* in_sizes, int n_in,
                              void* d_out, int out_size, void* d_ws, size_t ws_size,
                              hipStream_t stream) {
    const float* hidden = (const float*)d_in[0];
    const float* past_k = (const float*)d_in[1];
    const float* past_v = (const float*)d_in[2];
    const float* cosc = (const float*)d_in[3];
    const float* sinc = (const float*)d_in[4];
    const float* ln1w = (const float*)d_in[5];
    const float* ln1b = (const float*)d_in[6];
    const float* qkvw = (const float*)d_in[7];
    const float* qkvb = (const float*)d_in[8];
    const float* denw = (const float*)d_in[9];
    const float* denb = (const float*)d_in[10];
    const float* ln2w = (const float*)d_in[11];
    const float* ln2b = (const float*)d_in[12];
    const float* fc1w = (const float*)d_in[13];
    const float* fc1b = (const float*)d_in[14];
    const float* fc2w = (const float*)d_in[15];
    const float* fc2b = (const float*)d_in[16];
    const int* pos = (const int*)d_in[17];
    const int* blk = (const int*)d_in[18];
    const unsigned char* mask = (const unsigned char*)d_in[19];

    float* out_f = (float*)d_out;
    float* kout = out_f + HID;                    // [8193,32,128]
    float* vout = kout + (size_t)S_TOT * HID;     // [8193,32,128]

    float* ws = (float*)d_ws;
    float* resid1 = ws;                     // 4096
    float* qkvv   = ws + 4096;              // 12288
    float* qrot   = ws + 16384;             // 4096
    float* ctx    = ws + 20480;             // 4096
    float* hid2   = ws + 24576;             // 4096
    float* resid2 = ws + 28672;             // 4096
    float* mlpi   = ws + 32768;             // 16384
    float* pL     = ws + 49152;             // 32*512 = 16384
    float* pctx   = ws + 65536;             // 512*4096 = 2097152  (~8.7 MB total)

    ln_kernel<<<1, 256, 0, stream>>>(hidden, ln1w, ln1b, resid1);
    gemv_kernel<HID, 0><<<3 * HID / 4, 256, 0, stream>>>(qkvw, qkvb, resid1, qkvv, nullptr);
    rope_kv_kernel<<<NH, HD, 0, stream>>>(qkvv, cosc, sinc, pos, blk, qrot, kout, vout);
    attn_onepass<<<NCH, 512, 0, stream>>>(qrot, past_k, past_v, kout, vout, mask, pctx, pL);
    ctx_reduce<<<256, 256, 0, stream>>>(pctx, pL, ctx);
    gemv_kernel<HID, 1><<<HID / 4, 256, 0, stream>>>(denw, denb, ctx, hid2, resid1);
    ln_kernel<<<1, 256, 0, stream>>>(hid2, ln2w, ln2b, resid2);
    gemv_kernel<HID, 2><<<INNER / 4, 256, 0, stream>>>(fc1w, fc1b, resid2, mlpi, nullptr);
    gemv_wide_kernel<<<HID, 256, 0, stream>>>(fc2w, fc2b, mlpi, out_f, resid2);
}